// Round 2
// baseline (339.358 us; speedup 1.0000x reference)
//
#include <hip/hip_runtime.h>

typedef unsigned short u16;
typedef unsigned char u8;
typedef __attribute__((ext_vector_type(8))) short short8;
typedef __attribute__((ext_vector_type(2))) float f32x2;
typedef __attribute__((ext_vector_type(4))) float f32x4;
typedef __attribute__((ext_vector_type(4))) unsigned short us4;
typedef __attribute__((ext_vector_type(8))) unsigned short us8;
typedef __attribute__((ext_vector_type(4))) unsigned int u32x4;

#define N_NODES 50000
#define N_EDGES 800000
#define DIM 128
#define NINV (1.0f / 50000.0f)
#define SROW 136      /* LDS row stride (u16) */
#define NBKT 3125     /* node groups of 16: 50000/16 */
#define CAP 512       /* bucket capacity; mean fill 256, P(overflow) ~ e^-99 */
#define NPART 8
#define PART_K 391    /* ceil(3125/8) keys per XCD partition */

__device__ __forceinline__ float bf2f(u16 u) {
    union { unsigned int i; float f; } v; v.i = ((unsigned int)u) << 16; return v.f;
}
__device__ __forceinline__ u16 f2bf(float f) {
    union { float f; unsigned int i; } v; v.f = f;
    return (u16)((v.i + 0x7FFFu + ((v.i >> 16) & 1u)) >> 16);
}

// ---------------- prep: pack B1/B2, split x, XCD-partitioned edge bucketing ----------------
// blocks 0..15: pack B1; 16..31: pack B2; 32..32+splitB-1: split x;
// rest (3125*8): partitioned append (part = idx&7 pinned to XCD part, chunk = idx>>3):
// append (src<<4 | dst&15) to bucket[dst>>4] iff dst>>4 in partition's key range.
__global__ __launch_bounds__(256) void k_prep(
        const float* __restrict__ W1l, const float* __restrict__ W1r, u16* __restrict__ Bp1,
        const float* __restrict__ W2l, const float* __restrict__ W2r, u16* __restrict__ Bp2,
        const float* __restrict__ x, u16* __restrict__ xh, u8* __restrict__ xf8,
        const int* __restrict__ esrc, const int* __restrict__ edst,
        int* __restrict__ bcnt, unsigned* __restrict__ bucket, int splitB) {
    int b = blockIdx.x;
    if (b < 32) {
        const float* Wl = (b < 16) ? W1l : W2l;
        const float* Wr = (b < 16) ? W1r : W2r;
        u16* Bp = (b < 16) ? Bp1 : Bp2;
        int idx = (b & 15) * 256 + threadIdx.x;      // 0..4095
        int lane = idx & 63;
        int kc = (idx >> 6) & 7;
        int nt = idx >> 9;
        int q = lane >> 4, nn = lane & 15;
        int col = nt * 16 + nn;
        #pragma unroll
        for (int j = 0; j < 8; ++j) {
            int k = kc * 32 + q * 8 + j;
            float v = (k < 128) ? Wl[k * 128 + col] : Wr[(k - 128) * 128 + col];
            Bp[(long)idx * 8 + j] = f2bf(v);
        }
    } else if (b < 32 + splitB) {
        long i4 = ((long)(b - 32) * 256 + threadIdx.x) * 4;
        f32x4 v = *(const f32x4*)(x + i4);
        us4 h;
        #pragma unroll
        for (int j = 0; j < 4; ++j) h[j] = f2bf(v[j]);
        *(us4*)(xh + i4) = h;
        int p = __builtin_amdgcn_cvt_pk_fp8_f32(v[0], v[1], 0, false);
        p = __builtin_amdgcn_cvt_pk_fp8_f32(v[2], v[3], p, true);
        *(int*)(xf8 + i4) = p;
    } else {
        int hb = b - 32 - splitB;
        int part = hb & 7;                  // round-robin -> XCD 'part'
        int e = (hb >> 3) * 256 + threadIdx.x;
        if (e < N_EDGES) {
            int d = edst[e];
            int key = d >> 4;
            if ((unsigned)(key - part * PART_K) < (unsigned)PART_K) {
                int s = esrc[e];
                int pos = atomicAdd(&bcnt[key], 1);
                if (pos < CAP)
                    bucket[(long)key * CAP + pos] = ((unsigned)s << 4) | (unsigned)(d & 15);
            }
        }
    }
}

// decode 16 fp8 + (optional BN+relu) + accumulate
template<int BN>
__device__ __forceinline__ void acc_row16(u32x4 w,
        float sum[16], const float av[16], const float ov[16]) {
    float t[16];
    f32x2 p;
    #pragma unroll
    for (int h = 0; h < 4; ++h) {
        p = __builtin_amdgcn_cvt_pk_f32_fp8((int)w[h], false); t[h*4+0] = p[0]; t[h*4+1] = p[1];
        p = __builtin_amdgcn_cvt_pk_f32_fp8((int)w[h], true);  t[h*4+2] = p[0]; t[h*4+3] = p[1];
    }
    #pragma unroll
    for (int k = 0; k < 16; ++k) {
        float v = t[k];
        if (BN) { v = v * av[k] + ov[k]; v = v > 0.f ? v : 0.f; }
        sum[k] += v;
    }
}

// ---------------- fused AGG + GEMM + BN stats (512 threads) ----------------
// phase 0: LDS counting-sort of this block's bucket (hist == degree, indices land in LDS)
// phase 1: gather-mean, 32 lanes/node = 4 edge-quarters x 8 dim-groups
// phase 2: 8 waves, one 16-col MFMA tile each
template<int BN, int W8>
__global__ __launch_bounds__(512) void k_ag(
        const u8* __restrict__ fq, const u16* __restrict__ fh,
        const int* __restrict__ bcnt, const unsigned* __restrict__ bucket,
        const u16* __restrict__ Bph, const float* __restrict__ bias,
        const float* __restrict__ statsPrev, const float* __restrict__ gP,
        const float* __restrict__ btP,
        u16* __restrict__ h16, u8* __restrict__ h8, float* __restrict__ stats) {
    __shared__ u16 sA[16 * SROW];
    __shared__ float acS[256];
    __shared__ u16 sSort[CAP];
    __shared__ int sHist[16];
    __shared__ int sStart[16];
    __shared__ int sCur[16];
    int tid = threadIdx.x;
    long nodebase = (long)blockIdx.x * 16;       // 3125*16 == 50000 exact

    if (BN) {
        if (tid < 128) {
            float s = 0.f, qq = 0.f;
            #pragma unroll
            for (int b = 0; b < 8; ++b) {
                s  += statsPrev[b * 512 + tid];
                qq += statsPrev[b * 512 + 256 + tid];
            }
            float mu = s * NINV;
            float var = qq * NINV - mu * mu;
            float a = gP[tid] * rsqrtf(var + 1e-5f);
            acS[tid] = a;
            acS[128 + tid] = btP[tid] - mu * a;
        }
    }

    // ---- phase 0: stage bucket + LDS counting sort by node-low4 ----
    int cnt = bcnt[blockIdx.x];
    if (cnt > CAP) cnt = CAP;
    bool has = (tid < cnt);
    unsigned ent = 0u;
    if (has) ent = bucket[(long)blockIdx.x * CAP + tid];
    if (tid < 16) sHist[tid] = 0;
    __syncthreads();
    if (has) atomicAdd(&sHist[ent & 15u], 1);
    __syncthreads();
    if (tid == 0) {
        int acc = 0;
        #pragma unroll
        for (int i = 0; i < 16; ++i) { sStart[i] = acc; sCur[i] = acc; acc += sHist[i]; }
    }
    __syncthreads();
    if (has) {
        int p = atomicAdd(&sCur[ent & 15u], 1);
        sSort[p] = (u16)(ent >> 4);
    }
    __syncthreads();

    // ---- phase 1: gather-mean (fp8, 16B/lane, 4-way contiguous edge split) ----
    {
        int grp = tid >> 5;          // node 0..15
        int s5  = tid & 31;
        int sub = s5 >> 3;           // edge quarter 0..3
        int d16 = (s5 & 7) * 16;     // dim base
        int deg = sHist[grp];
        int st  = sStart[grp];
        int qn  = (deg + 3) >> 2;
        int js  = st + sub * qn;
        int je  = js + qn;
        int lim = st + deg;
        if (je > lim) je = lim;
        if (js > lim) js = lim;
        float av[16], ov[16];
        if (BN) {
            #pragma unroll
            for (int k = 0; k < 16; ++k) { av[k] = acS[d16 + k]; ov[k] = acS[128 + d16 + k]; }
        }
        float sum[16];
        #pragma unroll
        for (int k = 0; k < 16; ++k) sum[k] = 0.f;
        int j = js;
        for (; j + 3 < je; j += 4) {
            int i0 = sSort[j], i1 = sSort[j + 1], i2 = sSort[j + 2], i3 = sSort[j + 3];
            u32x4 w0 = *(const u32x4*)(fq + (long)i0 * DIM + d16);
            u32x4 w1 = *(const u32x4*)(fq + (long)i1 * DIM + d16);
            u32x4 w2 = *(const u32x4*)(fq + (long)i2 * DIM + d16);
            u32x4 w3 = *(const u32x4*)(fq + (long)i3 * DIM + d16);
            acc_row16<BN>(w0, sum, av, ov);
            acc_row16<BN>(w1, sum, av, ov);
            acc_row16<BN>(w2, sum, av, ov);
            acc_row16<BN>(w3, sum, av, ov);
        }
        for (; j < je; ++j) {
            int i0 = sSort[j];
            u32x4 w0 = *(const u32x4*)(fq + (long)i0 * DIM + d16);
            acc_row16<BN>(w0, sum, av, ov);
        }
        // combine 4 quarters (xor 8 and 16 stay within the node's 32 lanes)
        #pragma unroll
        for (int k = 0; k < 16; ++k) {
            sum[k] += __shfl_xor(sum[k], 8);
            sum[k] += __shfl_xor(sum[k], 16);
        }
        if (sub == 0) {
            float dn = (deg > 0) ? 1.f / (float)deg : 1.f;
            us8 r0, r1;
            #pragma unroll
            for (int k = 0; k < 8; ++k) {
                r0[k] = f2bf(sum[k] * dn);
                r1[k] = f2bf(sum[8 + k] * dn);
            }
            *(us8*)(sA + grp * SROW + d16) = r0;
            *(us8*)(sA + grp * SROW + d16 + 8) = r1;
        }
    }
    __syncthreads();

    // ---- phase 2: MFMA, 8 waves x one 16-col tile ----
    int cg = tid >> 6, lane = tid & 63;
    int q = lane >> 4, nn = lane & 15;
    long rc = nodebase + nn;

    short8 ah[8];
    #pragma unroll
    for (int kc = 0; kc < 4; ++kc)
        ah[kc] = *(const short8*)(sA + nn * SROW + kc * 32 + q * 8);
    #pragma unroll
    for (int kc = 0; kc < 4; ++kc) {
        int ko = kc * 32 + q * 8;
        us8 rv = *(const us8*)(fh + rc * DIM + ko);
        short8 t;
        if (BN) {
            #pragma unroll
            for (int j = 0; j < 8; ++j) {
                float v = bf2f(rv[j]) * acS[ko + j] + acS[128 + ko + j];
                t[j] = (short)f2bf(v > 0.f ? v : 0.f);
            }
        } else {
            #pragma unroll
            for (int j = 0; j < 8; ++j) t[j] = (short)rv[j];
        }
        ah[4 + kc] = t;
    }

    f32x4 acc = (f32x4){0.f, 0.f, 0.f, 0.f};
    #pragma unroll
    for (int kc = 0; kc < 8; ++kc) {
        short8 bh = *(const short8*)(Bph + (((cg * 8 + kc) * 64 + lane) << 3));
        acc = __builtin_amdgcn_mfma_f32_16x16x32_bf16(ah[kc], bh, acc, 0, 0, 0);
    }

    int bank = blockIdx.x & 7;
    int col = cg * 16 + nn;
    float bv = bias[col];
    float ps = 0.f, pq = 0.f;
    #pragma unroll
    for (int r = 0; r < 4; ++r) {
        float v = acc[r] + bv;
        long idx = (nodebase + q * 4 + r) * DIM + col;
        h16[idx] = f2bf(v);
        if (W8) {
            int pb = __builtin_amdgcn_cvt_pk_fp8_f32(v, v, 0, false);
            h8[idx] = (u8)(pb & 0xff);
        }
        ps += v; pq += v * v;
    }
    ps += __shfl_xor(ps, 16);
    ps += __shfl_xor(ps, 32);
    pq += __shfl_xor(pq, 16);
    pq += __shfl_xor(pq, 32);
    if (q == 0) {
        atomicAdd(&stats[bank * 512 + col], ps);
        atomicAdd(&stats[bank * 512 + 256 + col], pq);
    }
}

// out = relu(bn(h)+x); coeffs computed in-block from banked stats
__global__ __launch_bounds__(256) void k_bn_add_relu(
        const u16* __restrict__ h, const float* __restrict__ stats,
        const float* __restrict__ g, const float* __restrict__ bt,
        const float* __restrict__ x, float* __restrict__ outv) {
    __shared__ float acS[256];
    int tid = threadIdx.x;
    if (tid < 128) {
        float s = 0.f, qq = 0.f;
        #pragma unroll
        for (int b = 0; b < 8; ++b) {
            s  += stats[b * 512 + tid];
            qq += stats[b * 512 + 256 + tid];
        }
        float mu = s * NINV;
        float var = qq * NINV - mu * mu;
        float a = g[tid] * rsqrtf(var + 1e-5f);
        acS[tid] = a;
        acS[128 + tid] = bt[tid] - mu * a;
    }
    __syncthreads();
    long i8 = ((long)blockIdx.x * 256 + tid) * 8;
    int c = (int)(i8 & 127);
    us8 hv = *(const us8*)(h + i8);
    f32x4 x0 = *(const f32x4*)(x + i8);
    f32x4 x1 = *(const f32x4*)(x + i8 + 4);
    f32x4 r0, r1;
    #pragma unroll
    for (int j = 0; j < 4; ++j) {
        float v = bf2f(hv[j]) * acS[c + j] + acS[128 + c + j] + x0[j];
        r0[j] = v > 0.f ? v : 0.f;
        float w = bf2f(hv[4 + j]) * acS[c + 4 + j] + acS[128 + c + 4 + j] + x1[j];
        r1[j] = w > 0.f ? w : 0.f;
    }
    *(f32x4*)(outv + i8) = r0;
    *(f32x4*)(outv + i8 + 4) = r1;
}

extern "C" void kernel_launch(void* const* d_in, const int* in_sizes, int n_in,
                              void* d_out, int out_size, void* d_ws, size_t ws_size,
                              hipStream_t stream) {
    (void)in_sizes; (void)n_in; (void)out_size; (void)ws_size;
    const float* x   = (const float*)d_in[0];
    const int*   ei  = (const int*)d_in[1];
    const float* W1l = (const float*)d_in[2];
    const float* b1  = (const float*)d_in[3];
    const float* W1r = (const float*)d_in[4];
    const float* g1  = (const float*)d_in[5];
    const float* bt1 = (const float*)d_in[6];
    const float* W2l = (const float*)d_in[7];
    const float* b2  = (const float*)d_in[8];
    const float* W2r = (const float*)d_in[9];
    const float* g2  = (const float*)d_in[10];
    const float* bt2 = (const float*)d_in[11];
    float* out = (float*)d_out;

    const int* esrc = ei;
    const int* edst = ei + N_EDGES;

    char* ws = (char*)d_ws;
    size_t off = 0;
    auto alloc = [&](size_t bytes) { size_t p = off; off = (off + bytes + 255) & ~(size_t)255; return p; };
    float* stats1  = (float*)(ws + alloc(4096 * 4));   // 8 banks x 512 (sum@+col, sumsq@+256+col)
    float* stats2  = (float*)(ws + alloc(4096 * 4));
    int*   bcnt    = (int*)  (ws + alloc(NBKT * 4));
    size_t zero_bytes = off;                       // everything above must be zeroed
    unsigned* bucket = (unsigned*)(ws + alloc((size_t)NBKT * CAP * 4));
    u16*   xh      = (u16*)  (ws + alloc((size_t)N_NODES * DIM * 2));
    u8*    xf8     = (u8*)   (ws + alloc((size_t)N_NODES * DIM));
    u16*   hb1     = (u16*)  (ws + alloc((size_t)N_NODES * DIM * 2));  // raw h1 bf16
    u8*    h1f8    = (u8*)   (ws + alloc((size_t)N_NODES * DIM));     // raw h1 fp8
    u16*   hb2     = (u16*)  (ws + alloc((size_t)N_NODES * DIM * 2));  // raw h2 bf16
    u16*   Bp1h    = (u16*)  (ws + alloc(256 * 128 * 2));
    u16*   Bp2h    = (u16*)  (ws + alloc(256 * 128 * 2));

    hipMemsetAsync(ws, 0, zero_bytes, stream);

    const int AGB = N_NODES / 16;                    // 3125 exact
    const int EWB4 = (int)(((long)N_NODES * DIM) / 1024);  // 6250 exact
    const int EWB8 = (int)(((long)N_NODES * DIM) / 2048);  // 3125 exact
    const int EDGB = N_EDGES / 256;                  // 3125 exact
    const int FILLB = EDGB * NPART;                  // 25000: 8 partitioned passes
    const int PREPB = 32 + EWB4 + FILLB;             // pack + split + partitioned append

    // prep: pack both B + split x (bf16 + fp8) + XCD-partitioned edge bucketing
    k_prep<<<PREPB, 256, 0, stream>>>(W1l, W1r, Bp1h, W2l, W2r, Bp2h, x, xh, xf8,
                                      esrc, edst, bcnt, bucket, EWB4);

    // stage 1: fused agg+gemm on x (fp8 gather, bf16 root); writes h1 bf16 + fp8
    k_ag<0, 1><<<AGB, 512, 0, stream>>>(xf8, xh, bcnt, bucket, Bp1h, b1,
                                        stats1, g1, bt1, hb1, h1f8, stats1);

    // stage 2: fused agg+gemm on h1 with BN+relu at operand load (coeffs from stats1)
    k_ag<1, 0><<<AGB, 512, 0, stream>>>(h1f8, hb1, bcnt, bucket, Bp2h, b2,
                                        stats1, g1, bt1, hb2, h1f8, stats2);

    // epilogue: out = relu(bn(h2) + x), coeffs from stats2
    k_bn_add_relu<<<EWB8, 256, 0, stream>>>(hb2, stats2, g2, bt2, x, out);
}

// Round 3
// 257.691 us; speedup vs baseline: 1.3169x; 1.3169x over previous
//
#include <hip/hip_runtime.h>

typedef unsigned short u16;
typedef unsigned char u8;
typedef __attribute__((ext_vector_type(8))) short short8;
typedef __attribute__((ext_vector_type(2))) float f32x2;
typedef __attribute__((ext_vector_type(4))) float f32x4;
typedef __attribute__((ext_vector_type(4))) int i32x4;
typedef __attribute__((ext_vector_type(4))) unsigned short us4;
typedef __attribute__((ext_vector_type(8))) unsigned short us8;
typedef __attribute__((ext_vector_type(4))) unsigned int u32x4;

#define N_NODES 50000
#define N_EDGES 800000
#define DIM 128
#define NINV (1.0f / 50000.0f)
#define SROW 136      /* LDS row stride (u16) */
#define NBKT 3125     /* node groups of 16: 50000/16 */
#define CAP 512       /* bucket capacity; mean fill 256, P(overflow) ~ e^-99 */

__device__ __forceinline__ float bf2f(u16 u) {
    union { unsigned int i; float f; } v; v.i = ((unsigned int)u) << 16; return v.f;
}
__device__ __forceinline__ u16 f2bf(float f) {
    union { float f; unsigned int i; } v; v.f = f;
    return (u16)((v.i + 0x7FFFu + ((v.i >> 16) & 1u)) >> 16);
}

// ---------------- prep: pack B1/B2, split x, single-pass edge bucketing ----------------
// blocks 0..15: pack B1; 16..31: pack B2; 32..32+splitB-1: split x;
// rest (782): one pass, 4 edges/thread; append (src<<4 | dst&15) to bucket[dst>>4].
// bcnt is padded to 1 counter per 64B line (stride 16) to kill atomic line contention.
__global__ __launch_bounds__(256) void k_prep(
        const float* __restrict__ W1l, const float* __restrict__ W1r, u16* __restrict__ Bp1,
        const float* __restrict__ W2l, const float* __restrict__ W2r, u16* __restrict__ Bp2,
        const float* __restrict__ x, u16* __restrict__ xh, u8* __restrict__ xf8,
        const int* __restrict__ esrc, const int* __restrict__ edst,
        int* __restrict__ bcnt, unsigned* __restrict__ bucket, int splitB) {
    int b = blockIdx.x;
    if (b < 32) {
        const float* Wl = (b < 16) ? W1l : W2l;
        const float* Wr = (b < 16) ? W1r : W2r;
        u16* Bp = (b < 16) ? Bp1 : Bp2;
        int idx = (b & 15) * 256 + threadIdx.x;      // 0..4095
        int lane = idx & 63;
        int kc = (idx >> 6) & 7;
        int nt = idx >> 9;
        int q = lane >> 4, nn = lane & 15;
        int col = nt * 16 + nn;
        #pragma unroll
        for (int j = 0; j < 8; ++j) {
            int k = kc * 32 + q * 8 + j;
            float v = (k < 128) ? Wl[k * 128 + col] : Wr[(k - 128) * 128 + col];
            Bp[(long)idx * 8 + j] = f2bf(v);
        }
    } else if (b < 32 + splitB) {
        long i4 = ((long)(b - 32) * 256 + threadIdx.x) * 4;
        f32x4 v = *(const f32x4*)(x + i4);
        us4 h;
        #pragma unroll
        for (int j = 0; j < 4; ++j) h[j] = f2bf(v[j]);
        *(us4*)(xh + i4) = h;
        int p = __builtin_amdgcn_cvt_pk_fp8_f32(v[0], v[1], 0, false);
        p = __builtin_amdgcn_cvt_pk_fp8_f32(v[2], v[3], p, true);
        *(int*)(xf8 + i4) = p;
    } else {
        int e4 = (b - 32 - splitB) * 1024 + threadIdx.x * 4;
        if (e4 < N_EDGES) {   // N_EDGES % 4 == 0, so full int4 is in-range
            i32x4 d4 = *(const i32x4*)(edst + e4);
            i32x4 s4 = *(const i32x4*)(esrc + e4);
            #pragma unroll
            for (int j = 0; j < 4; ++j) {
                int d = d4[j];
                int key = d >> 4;
                int pos = atomicAdd(&bcnt[key << 4], 1);
                if (pos < CAP)
                    bucket[(long)key * CAP + pos] = ((unsigned)s4[j] << 4) | (unsigned)(d & 15);
            }
        }
    }
}

// decode 16 fp8 + (optional BN+relu) + accumulate
template<int BN>
__device__ __forceinline__ void acc_row16(u32x4 w,
        float sum[16], const float av[16], const float ov[16]) {
    float t[16];
    f32x2 p;
    #pragma unroll
    for (int h = 0; h < 4; ++h) {
        p = __builtin_amdgcn_cvt_pk_f32_fp8((int)w[h], false); t[h*4+0] = p[0]; t[h*4+1] = p[1];
        p = __builtin_amdgcn_cvt_pk_f32_fp8((int)w[h], true);  t[h*4+2] = p[0]; t[h*4+3] = p[1];
    }
    #pragma unroll
    for (int k = 0; k < 16; ++k) {
        float v = t[k];
        if (BN) { v = v * av[k] + ov[k]; v = v > 0.f ? v : 0.f; }
        sum[k] += v;
    }
}

// ---------------- fused AGG + GEMM + BN stats (512 threads) ----------------
// phase 0: LDS counting-sort of this block's bucket (hist == degree, indices land in LDS)
// phase 1: gather-mean, 32 lanes/node = 4 edge-quarters x 8 dim-groups
// phase 2: 8 waves, one 16-col MFMA tile each
template<int BN, int W8>
__global__ __launch_bounds__(512) void k_ag(
        const u8* __restrict__ fq, const u16* __restrict__ fh,
        const int* __restrict__ bcnt, const unsigned* __restrict__ bucket,
        const u16* __restrict__ Bph, const float* __restrict__ bias,
        const float* __restrict__ statsPrev, const float* __restrict__ gP,
        const float* __restrict__ btP,
        u16* __restrict__ h16, u8* __restrict__ h8, float* __restrict__ stats) {
    __shared__ u16 sA[16 * SROW];
    __shared__ float acS[256];
    __shared__ u16 sSort[CAP];
    __shared__ int sHist[16];
    __shared__ int sStart[16];
    __shared__ int sCur[16];
    int tid = threadIdx.x;
    long nodebase = (long)blockIdx.x * 16;       // 3125*16 == 50000 exact

    if (BN) {
        if (tid < 128) {
            float s = 0.f, qq = 0.f;
            #pragma unroll
            for (int b = 0; b < 8; ++b) {
                s  += statsPrev[b * 512 + tid];
                qq += statsPrev[b * 512 + 256 + tid];
            }
            float mu = s * NINV;
            float var = qq * NINV - mu * mu;
            float a = gP[tid] * rsqrtf(var + 1e-5f);
            acS[tid] = a;
            acS[128 + tid] = btP[tid] - mu * a;
        }
    }

    // ---- phase 0: stage bucket + LDS counting sort by node-low4 ----
    int cnt = bcnt[blockIdx.x << 4];
    if (cnt > CAP) cnt = CAP;
    bool has = (tid < cnt);
    unsigned ent = 0u;
    if (has) ent = bucket[(long)blockIdx.x * CAP + tid];
    if (tid < 16) sHist[tid] = 0;
    __syncthreads();
    if (has) atomicAdd(&sHist[ent & 15u], 1);
    __syncthreads();
    if (tid == 0) {
        int acc = 0;
        #pragma unroll
        for (int i = 0; i < 16; ++i) { sStart[i] = acc; sCur[i] = acc; acc += sHist[i]; }
    }
    __syncthreads();
    if (has) {
        int p = atomicAdd(&sCur[ent & 15u], 1);
        sSort[p] = (u16)(ent >> 4);
    }
    __syncthreads();

    // ---- phase 1: gather-mean (fp8, 16B/lane, 4-way contiguous edge split) ----
    {
        int grp = tid >> 5;          // node 0..15
        int s5  = tid & 31;
        int sub = s5 >> 3;           // edge quarter 0..3
        int d16 = (s5 & 7) * 16;     // dim base
        int deg = sHist[grp];
        int st  = sStart[grp];
        int qn  = (deg + 3) >> 2;
        int js  = st + sub * qn;
        int je  = js + qn;
        int lim = st + deg;
        if (je > lim) je = lim;
        if (js > lim) js = lim;
        float av[16], ov[16];
        if (BN) {
            #pragma unroll
            for (int k = 0; k < 16; ++k) { av[k] = acS[d16 + k]; ov[k] = acS[128 + d16 + k]; }
        }
        float sum[16];
        #pragma unroll
        for (int k = 0; k < 16; ++k) sum[k] = 0.f;
        int j = js;
        for (; j + 3 < je; j += 4) {
            int i0 = sSort[j], i1 = sSort[j + 1], i2 = sSort[j + 2], i3 = sSort[j + 3];
            u32x4 w0 = *(const u32x4*)(fq + (long)i0 * DIM + d16);
            u32x4 w1 = *(const u32x4*)(fq + (long)i1 * DIM + d16);
            u32x4 w2 = *(const u32x4*)(fq + (long)i2 * DIM + d16);
            u32x4 w3 = *(const u32x4*)(fq + (long)i3 * DIM + d16);
            acc_row16<BN>(w0, sum, av, ov);
            acc_row16<BN>(w1, sum, av, ov);
            acc_row16<BN>(w2, sum, av, ov);
            acc_row16<BN>(w3, sum, av, ov);
        }
        for (; j < je; ++j) {
            int i0 = sSort[j];
            u32x4 w0 = *(const u32x4*)(fq + (long)i0 * DIM + d16);
            acc_row16<BN>(w0, sum, av, ov);
        }
        // combine 4 quarters (xor 8 and 16 stay within the node's 32 lanes)
        #pragma unroll
        for (int k = 0; k < 16; ++k) {
            sum[k] += __shfl_xor(sum[k], 8);
            sum[k] += __shfl_xor(sum[k], 16);
        }
        if (sub == 0) {
            float dn = (deg > 0) ? 1.f / (float)deg : 1.f;
            us8 r0, r1;
            #pragma unroll
            for (int k = 0; k < 8; ++k) {
                r0[k] = f2bf(sum[k] * dn);
                r1[k] = f2bf(sum[8 + k] * dn);
            }
            *(us8*)(sA + grp * SROW + d16) = r0;
            *(us8*)(sA + grp * SROW + d16 + 8) = r1;
        }
    }
    __syncthreads();

    // ---- phase 2: MFMA, 8 waves x one 16-col tile ----
    int cg = tid >> 6, lane = tid & 63;
    int q = lane >> 4, nn = lane & 15;
    long rc = nodebase + nn;

    short8 ah[8];
    #pragma unroll
    for (int kc = 0; kc < 4; ++kc)
        ah[kc] = *(const short8*)(sA + nn * SROW + kc * 32 + q * 8);
    #pragma unroll
    for (int kc = 0; kc < 4; ++kc) {
        int ko = kc * 32 + q * 8;
        us8 rv = *(const us8*)(fh + rc * DIM + ko);
        short8 t;
        if (BN) {
            #pragma unroll
            for (int j = 0; j < 8; ++j) {
                float v = bf2f(rv[j]) * acS[ko + j] + acS[128 + ko + j];
                t[j] = (short)f2bf(v > 0.f ? v : 0.f);
            }
        } else {
            #pragma unroll
            for (int j = 0; j < 8; ++j) t[j] = (short)rv[j];
        }
        ah[4 + kc] = t;
    }

    f32x4 acc = (f32x4){0.f, 0.f, 0.f, 0.f};
    #pragma unroll
    for (int kc = 0; kc < 8; ++kc) {
        short8 bh = *(const short8*)(Bph + (((cg * 8 + kc) * 64 + lane) << 3));
        acc = __builtin_amdgcn_mfma_f32_16x16x32_bf16(ah[kc], bh, acc, 0, 0, 0);
    }

    int bank = blockIdx.x & 7;
    int col = cg * 16 + nn;
    float bv = bias[col];
    float ps = 0.f, pq = 0.f;
    #pragma unroll
    for (int r = 0; r < 4; ++r) {
        float v = acc[r] + bv;
        long idx = (nodebase + q * 4 + r) * DIM + col;
        h16[idx] = f2bf(v);
        if (W8) {
            int pb = __builtin_amdgcn_cvt_pk_fp8_f32(v, v, 0, false);
            h8[idx] = (u8)(pb & 0xff);
        }
        ps += v; pq += v * v;
    }
    ps += __shfl_xor(ps, 16);
    ps += __shfl_xor(ps, 32);
    pq += __shfl_xor(pq, 16);
    pq += __shfl_xor(pq, 32);
    if (q == 0) {
        atomicAdd(&stats[bank * 512 + col], ps);
        atomicAdd(&stats[bank * 512 + 256 + col], pq);
    }
}

// out = relu(bn(h)+x); coeffs computed in-block from banked stats
__global__ __launch_bounds__(256) void k_bn_add_relu(
        const u16* __restrict__ h, const float* __restrict__ stats,
        const float* __restrict__ g, const float* __restrict__ bt,
        const float* __restrict__ x, float* __restrict__ outv) {
    __shared__ float acS[256];
    int tid = threadIdx.x;
    if (tid < 128) {
        float s = 0.f, qq = 0.f;
        #pragma unroll
        for (int b = 0; b < 8; ++b) {
            s  += stats[b * 512 + tid];
            qq += stats[b * 512 + 256 + tid];
        }
        float mu = s * NINV;
        float var = qq * NINV - mu * mu;
        float a = g[tid] * rsqrtf(var + 1e-5f);
        acS[tid] = a;
        acS[128 + tid] = bt[tid] - mu * a;
    }
    __syncthreads();
    long i8 = ((long)blockIdx.x * 256 + tid) * 8;
    int c = (int)(i8 & 127);
    us8 hv = *(const us8*)(h + i8);
    f32x4 x0 = *(const f32x4*)(x + i8);
    f32x4 x1 = *(const f32x4*)(x + i8 + 4);
    f32x4 r0, r1;
    #pragma unroll
    for (int j = 0; j < 4; ++j) {
        float v = bf2f(hv[j]) * acS[c + j] + acS[128 + c + j] + x0[j];
        r0[j] = v > 0.f ? v : 0.f;
        float w = bf2f(hv[4 + j]) * acS[c + 4 + j] + acS[128 + c + 4 + j] + x1[j];
        r1[j] = w > 0.f ? w : 0.f;
    }
    *(f32x4*)(outv + i8) = r0;
    *(f32x4*)(outv + i8 + 4) = r1;
}

extern "C" void kernel_launch(void* const* d_in, const int* in_sizes, int n_in,
                              void* d_out, int out_size, void* d_ws, size_t ws_size,
                              hipStream_t stream) {
    (void)in_sizes; (void)n_in; (void)out_size; (void)ws_size;
    const float* x   = (const float*)d_in[0];
    const int*   ei  = (const int*)d_in[1];
    const float* W1l = (const float*)d_in[2];
    const float* b1  = (const float*)d_in[3];
    const float* W1r = (const float*)d_in[4];
    const float* g1  = (const float*)d_in[5];
    const float* bt1 = (const float*)d_in[6];
    const float* W2l = (const float*)d_in[7];
    const float* b2  = (const float*)d_in[8];
    const float* W2r = (const float*)d_in[9];
    const float* g2  = (const float*)d_in[10];
    const float* bt2 = (const float*)d_in[11];
    float* out = (float*)d_out;

    const int* esrc = ei;
    const int* edst = ei + N_EDGES;

    char* ws = (char*)d_ws;
    size_t off = 0;
    auto alloc = [&](size_t bytes) { size_t p = off; off = (off + bytes + 255) & ~(size_t)255; return p; };
    float* stats1  = (float*)(ws + alloc(4096 * 4));   // 8 banks x 512 (sum@+col, sumsq@+256+col)
    float* stats2  = (float*)(ws + alloc(4096 * 4));
    int*   bcnt    = (int*)  (ws + alloc((size_t)NBKT * 16 * 4));  // 1 counter / 64B line
    size_t zero_bytes = off;                       // everything above must be zeroed
    unsigned* bucket = (unsigned*)(ws + alloc((size_t)NBKT * CAP * 4));
    u16*   xh      = (u16*)  (ws + alloc((size_t)N_NODES * DIM * 2));
    u8*    xf8     = (u8*)   (ws + alloc((size_t)N_NODES * DIM));
    u16*   hb1     = (u16*)  (ws + alloc((size_t)N_NODES * DIM * 2));  // raw h1 bf16
    u8*    h1f8    = (u8*)   (ws + alloc((size_t)N_NODES * DIM));     // raw h1 fp8
    u16*   hb2     = (u16*)  (ws + alloc((size_t)N_NODES * DIM * 2));  // raw h2 bf16
    u16*   Bp1h    = (u16*)  (ws + alloc(256 * 128 * 2));
    u16*   Bp2h    = (u16*)  (ws + alloc(256 * 128 * 2));

    hipMemsetAsync(ws, 0, zero_bytes, stream);

    const int AGB = N_NODES / 16;                    // 3125 exact
    const int EWB4 = (int)(((long)N_NODES * DIM) / 1024);  // 6250 exact
    const int EWB8 = (int)(((long)N_NODES * DIM) / 2048);  // 3125 exact
    const int EDGB = (N_EDGES + 1023) / 1024;        // 782 (4 edges/thread)
    const int PREPB = 32 + EWB4 + EDGB;              // pack + split + bucket append

    // prep: pack both B + split x (bf16 + fp8) + single-pass edge bucketing
    k_prep<<<PREPB, 256, 0, stream>>>(W1l, W1r, Bp1h, W2l, W2r, Bp2h, x, xh, xf8,
                                      esrc, edst, bcnt, bucket, EWB4);

    // stage 1: fused agg+gemm on x (fp8 gather, bf16 root); writes h1 bf16 + fp8
    k_ag<0, 1><<<AGB, 512, 0, stream>>>(xf8, xh, bcnt, bucket, Bp1h, b1,
                                        stats1, g1, bt1, hb1, h1f8, stats1);

    // stage 2: fused agg+gemm on h1 with BN+relu at operand load (coeffs from stats1)
    k_ag<1, 0><<<AGB, 512, 0, stream>>>(h1f8, hb1, bcnt, bucket, Bp2h, b2,
                                        stats1, g1, bt1, hb2, h1f8, stats2);

    // epilogue: out = relu(bn(h2) + x), coeffs from stats2
    k_bn_add_relu<<<EWB8, 256, 0, stream>>>(hb2, stats2, g2, bt2, x, out);
}

// Round 4
// 232.674 us; speedup vs baseline: 1.4585x; 1.1075x over previous
//
#include <hip/hip_runtime.h>

typedef unsigned short u16;
typedef unsigned char u8;
typedef __attribute__((ext_vector_type(8))) short short8;
typedef __attribute__((ext_vector_type(2))) float f32x2;
typedef __attribute__((ext_vector_type(4))) float f32x4;
typedef __attribute__((ext_vector_type(4))) int i32x4;
typedef __attribute__((ext_vector_type(4))) unsigned short us4;
typedef __attribute__((ext_vector_type(8))) unsigned short us8;
typedef __attribute__((ext_vector_type(4))) unsigned int u32x4;

#define N_NODES 50000
#define N_EDGES 800000
#define DIM 128
#define NINV (1.0f / 50000.0f)
#define SROW 136      /* LDS row stride (u16) */
#define NBKT 3125     /* node groups of 16: 50000/16 */
#define CAP 512       /* bucket capacity; mean fill 256, P(overflow) ~ e^-99 */

__device__ __forceinline__ float bf2f(u16 u) {
    union { unsigned int i; float f; } v; v.i = ((unsigned int)u) << 16; return v.f;
}
__device__ __forceinline__ u16 f2bf(float f) {
    union { float f; unsigned int i; } v; v.f = f;
    return (u16)((v.i + 0x7FFFu + ((v.i >> 16) & 1u)) >> 16);
}

// ---------------- prep: pack B1/B2, split x, single-pass edge bucketing ----------------
// blocks 0..15: pack B1; 16..31: pack B2; 32..32+splitB-1: split x;
// rest (782): one pass, 4 edges/thread; append (src<<4 | dst&15) to bucket[dst>>4].
// bcnt is padded to 1 counter per 64B line (stride 16) to kill atomic line contention.
__global__ __launch_bounds__(256) void k_prep(
        const float* __restrict__ W1l, const float* __restrict__ W1r, u16* __restrict__ Bp1,
        const float* __restrict__ W2l, const float* __restrict__ W2r, u16* __restrict__ Bp2,
        const float* __restrict__ x, u16* __restrict__ xh, u8* __restrict__ xf8,
        const int* __restrict__ esrc, const int* __restrict__ edst,
        int* __restrict__ bcnt, unsigned* __restrict__ bucket, int splitB) {
    int b = blockIdx.x;
    if (b < 32) {
        const float* Wl = (b < 16) ? W1l : W2l;
        const float* Wr = (b < 16) ? W1r : W2r;
        u16* Bp = (b < 16) ? Bp1 : Bp2;
        int idx = (b & 15) * 256 + threadIdx.x;      // 0..4095
        int lane = idx & 63;
        int kc = (idx >> 6) & 7;
        int nt = idx >> 9;
        int q = lane >> 4, nn = lane & 15;
        int col = nt * 16 + nn;
        #pragma unroll
        for (int j = 0; j < 8; ++j) {
            int k = kc * 32 + q * 8 + j;
            float v = (k < 128) ? Wl[k * 128 + col] : Wr[(k - 128) * 128 + col];
            Bp[(long)idx * 8 + j] = f2bf(v);
        }
    } else if (b < 32 + splitB) {
        long i4 = ((long)(b - 32) * 256 + threadIdx.x) * 4;
        f32x4 v = *(const f32x4*)(x + i4);
        us4 h;
        #pragma unroll
        for (int j = 0; j < 4; ++j) h[j] = f2bf(v[j]);
        *(us4*)(xh + i4) = h;
        int p = __builtin_amdgcn_cvt_pk_fp8_f32(v[0], v[1], 0, false);
        p = __builtin_amdgcn_cvt_pk_fp8_f32(v[2], v[3], p, true);
        *(int*)(xf8 + i4) = p;
    } else {
        int e4 = (b - 32 - splitB) * 1024 + threadIdx.x * 4;
        if (e4 < N_EDGES) {   // N_EDGES % 4 == 0, so full int4 is in-range
            i32x4 d4 = *(const i32x4*)(edst + e4);
            i32x4 s4 = *(const i32x4*)(esrc + e4);
            #pragma unroll
            for (int j = 0; j < 4; ++j) {
                int d = d4[j];
                int key = d >> 4;
                int pos = atomicAdd(&bcnt[key << 4], 1);
                if (pos < CAP)
                    bucket[(long)key * CAP + pos] = ((unsigned)s4[j] << 4) | (unsigned)(d & 15);
            }
        }
    }
}

// ---------------- per-group counting sort: bucket -> sorted col_srt + header ----------------
// 3125 tiny blocks, high residency -> sort latency overlaps across blocks.
// hdr[bid*32 + i]   = group-local start of node i's edges (u16)
// hdr[bid*32+16+i]  = degree of node i (u16)
__global__ __launch_bounds__(256) void k_sort(
        const int* __restrict__ bcnt, const unsigned* __restrict__ bucket,
        u16* __restrict__ col_srt, u16* __restrict__ hdr) {
    __shared__ int sHist[16], sStart[16], sCur[16];
    __shared__ u16 sSort[CAP];
    int tid = threadIdx.x;
    int bid = blockIdx.x;
    int cnt = bcnt[bid << 4]; if (cnt > CAP) cnt = CAP;
    bool h0 = tid < cnt, h1 = tid + 256 < cnt;
    unsigned e0 = 0u, e1 = 0u;
    if (h0) e0 = bucket[(long)bid * CAP + tid];
    if (h1) e1 = bucket[(long)bid * CAP + tid + 256];
    if (tid < 16) sHist[tid] = 0;
    __syncthreads();
    if (h0) atomicAdd(&sHist[e0 & 15u], 1);
    if (h1) atomicAdd(&sHist[e1 & 15u], 1);
    __syncthreads();
    if (tid == 0) {
        int acc = 0;
        #pragma unroll
        for (int i = 0; i < 16; ++i) { sStart[i] = acc; sCur[i] = acc; acc += sHist[i]; }
    }
    __syncthreads();
    if (h0) { int p = atomicAdd(&sCur[e0 & 15u], 1); sSort[p] = (u16)(e0 >> 4); }
    if (h1) { int p = atomicAdd(&sCur[e1 & 15u], 1); sSort[p] = (u16)(e1 >> 4); }
    __syncthreads();
    if (h0) col_srt[(long)bid * CAP + tid] = sSort[tid];
    if (h1) col_srt[(long)bid * CAP + tid + 256] = sSort[tid + 256];
    if (tid < 16) {
        hdr[bid * 32 + tid] = (u16)sStart[tid];
        hdr[bid * 32 + 16 + tid] = (u16)sHist[tid];
    }
}

// decode 16 fp8 + (optional BN+relu) + accumulate
template<int BN>
__device__ __forceinline__ void acc_row16(u32x4 w,
        float sum[16], const float av[16], const float ov[16]) {
    float t[16];
    f32x2 p;
    #pragma unroll
    for (int h = 0; h < 4; ++h) {
        p = __builtin_amdgcn_cvt_pk_f32_fp8((int)w[h], false); t[h*4+0] = p[0]; t[h*4+1] = p[1];
        p = __builtin_amdgcn_cvt_pk_f32_fp8((int)w[h], true);  t[h*4+2] = p[0]; t[h*4+3] = p[1];
    }
    #pragma unroll
    for (int k = 0; k < 16; ++k) {
        float v = t[k];
        if (BN) { v = v * av[k] + ov[k]; v = v > 0.f ? v : 0.f; }
        sum[k] += v;
    }
}

// ---------------- fused AGG + GEMM + BN stats (round-0 structure, 256 threads) ----------------
template<int BN, int W8>
__global__ __launch_bounds__(256) void k_ag(
        const u8* __restrict__ fq, const u16* __restrict__ fh,
        const u16* __restrict__ hdr, const u16* __restrict__ col_srt,
        const u16* __restrict__ Bph, const float* __restrict__ bias,
        const float* __restrict__ statsPrev, const float* __restrict__ gP,
        const float* __restrict__ btP,
        u16* __restrict__ h16, u8* __restrict__ h8, float* __restrict__ stats) {
    __shared__ u16 sA[16 * SROW];
    __shared__ float acS[256];
    int tid = threadIdx.x;
    long nodebase = (long)blockIdx.x * 16;       // 3125*16 == 50000 exact

    if (BN) {
        if (tid < 128) {
            float s = 0.f, qq = 0.f;
            #pragma unroll
            for (int b = 0; b < 8; ++b) {
                s  += statsPrev[b * 512 + tid];
                qq += statsPrev[b * 512 + 256 + tid];
            }
            float mu = s * NINV;
            float var = qq * NINV - mu * mu;
            float a = gP[tid] * rsqrtf(var + 1e-5f);
            acS[tid] = a;
            acS[128 + tid] = btP[tid] - mu * a;
        }
        __syncthreads();
    }

    // ---- phase 1: gather-mean (fp8, 16B/lane, even/odd edge split) ----
    {
        int grp = tid >> 4;          // node 0..15
        int g   = tid & 15;
        int sub = g >> 3;            // 0: even edges, 1: odd edges
        int gl  = g & 7;
        int d16 = gl * 16;           // dim base
        const u16* cs = col_srt + (long)blockIdx.x * CAP;
        int st  = hdr[blockIdx.x * 32 + grp];
        int deg = hdr[blockIdx.x * 32 + 16 + grp];
        int s = st, e = st + deg;
        float av[16], ov[16];
        if (BN) {
            #pragma unroll
            for (int k = 0; k < 16; ++k) { av[k] = acS[d16 + k]; ov[k] = acS[128 + d16 + k]; }
        }
        float sum[16];
        #pragma unroll
        for (int k = 0; k < 16; ++k) sum[k] = 0.f;
        int j = s + sub;
        for (; j + 6 < e; j += 8) {
            int i0 = cs[j], i1 = cs[j + 2], i2 = cs[j + 4], i3 = cs[j + 6];
            u32x4 w0 = *(const u32x4*)(fq + (long)i0 * DIM + d16);
            u32x4 w1 = *(const u32x4*)(fq + (long)i1 * DIM + d16);
            u32x4 w2 = *(const u32x4*)(fq + (long)i2 * DIM + d16);
            u32x4 w3 = *(const u32x4*)(fq + (long)i3 * DIM + d16);
            acc_row16<BN>(w0, sum, av, ov);
            acc_row16<BN>(w1, sum, av, ov);
            acc_row16<BN>(w2, sum, av, ov);
            acc_row16<BN>(w3, sum, av, ov);
        }
        for (; j < e; j += 2) {
            int i0 = cs[j];
            u32x4 w0 = *(const u32x4*)(fq + (long)i0 * DIM + d16);
            acc_row16<BN>(w0, sum, av, ov);
        }
        // combine even/odd halves
        #pragma unroll
        for (int k = 0; k < 16; ++k) sum[k] += __shfl_xor(sum[k], 8);
        if (sub == 0) {
            float dn = (deg > 0) ? 1.f / (float)deg : 1.f;
            us8 r0, r1;
            #pragma unroll
            for (int k = 0; k < 8; ++k) {
                r0[k] = f2bf(sum[k] * dn);
                r1[k] = f2bf(sum[8 + k] * dn);
            }
            *(us8*)(sA + grp * SROW + d16) = r0;
            *(us8*)(sA + grp * SROW + d16 + 8) = r1;
        }
    }
    __syncthreads();

    // ---- phase 2: MFMA ----
    int cg = tid >> 6, lane = tid & 63;
    int q = lane >> 4, nn = lane & 15;
    long rc = nodebase + nn;

    short8 ah[8];
    #pragma unroll
    for (int kc = 0; kc < 4; ++kc)
        ah[kc] = *(const short8*)(sA + nn * SROW + kc * 32 + q * 8);
    #pragma unroll
    for (int kc = 0; kc < 4; ++kc) {
        int ko = kc * 32 + q * 8;
        us8 rv = *(const us8*)(fh + rc * DIM + ko);
        short8 t;
        if (BN) {
            #pragma unroll
            for (int j = 0; j < 8; ++j) {
                float v = bf2f(rv[j]) * acS[ko + j] + acS[128 + ko + j];
                t[j] = (short)f2bf(v > 0.f ? v : 0.f);
            }
        } else {
            #pragma unroll
            for (int j = 0; j < 8; ++j) t[j] = (short)rv[j];
        }
        ah[4 + kc] = t;
    }

    f32x4 acc[2];
    acc[0] = (f32x4){0.f, 0.f, 0.f, 0.f};
    acc[1] = (f32x4){0.f, 0.f, 0.f, 0.f};

    #pragma unroll
    for (int kc = 0; kc < 8; ++kc) {
        #pragma unroll
        for (int nt = 0; nt < 2; ++nt) {
            int ntg = cg * 2 + nt;
            short8 bh = *(const short8*)(Bph + (((ntg * 8 + kc) * 64 + lane) << 3));
            acc[nt] = __builtin_amdgcn_mfma_f32_16x16x32_bf16(ah[kc], bh, acc[nt], 0, 0, 0);
        }
    }

    int bank = blockIdx.x & 7;
    #pragma unroll
    for (int nt = 0; nt < 2; ++nt) {
        int col = cg * 32 + nt * 16 + nn;
        float bv = bias[col];
        float ps = 0.f, pq = 0.f;
        #pragma unroll
        for (int r = 0; r < 4; ++r) {
            float v = acc[nt][r] + bv;
            long idx = (nodebase + q * 4 + r) * DIM + col;
            h16[idx] = f2bf(v);
            if (W8) {
                int pb = __builtin_amdgcn_cvt_pk_fp8_f32(v, v, 0, false);
                h8[idx] = (u8)(pb & 0xff);
            }
            ps += v; pq += v * v;
        }
        ps += __shfl_xor(ps, 16);
        ps += __shfl_xor(ps, 32);
        pq += __shfl_xor(pq, 16);
        pq += __shfl_xor(pq, 32);
        if (q == 0) {
            atomicAdd(&stats[bank * 512 + col], ps);
            atomicAdd(&stats[bank * 512 + 256 + col], pq);
        }
    }
}

// out = relu(bn(h)+x); coeffs computed in-block from banked stats
__global__ __launch_bounds__(256) void k_bn_add_relu(
        const u16* __restrict__ h, const float* __restrict__ stats,
        const float* __restrict__ g, const float* __restrict__ bt,
        const float* __restrict__ x, float* __restrict__ outv) {
    __shared__ float acS[256];
    int tid = threadIdx.x;
    if (tid < 128) {
        float s = 0.f, qq = 0.f;
        #pragma unroll
        for (int b = 0; b < 8; ++b) {
            s  += stats[b * 512 + tid];
            qq += stats[b * 512 + 256 + tid];
        }
        float mu = s * NINV;
        float var = qq * NINV - mu * mu;
        float a = g[tid] * rsqrtf(var + 1e-5f);
        acS[tid] = a;
        acS[128 + tid] = bt[tid] - mu * a;
    }
    __syncthreads();
    long i8 = ((long)blockIdx.x * 256 + tid) * 8;
    int c = (int)(i8 & 127);
    us8 hv = *(const us8*)(h + i8);
    f32x4 x0 = *(const f32x4*)(x + i8);
    f32x4 x1 = *(const f32x4*)(x + i8 + 4);
    f32x4 r0, r1;
    #pragma unroll
    for (int j = 0; j < 4; ++j) {
        float v = bf2f(hv[j]) * acS[c + j] + acS[128 + c + j] + x0[j];
        r0[j] = v > 0.f ? v : 0.f;
        float w = bf2f(hv[4 + j]) * acS[c + 4 + j] + acS[128 + c + 4 + j] + x1[j];
        r1[j] = w > 0.f ? w : 0.f;
    }
    *(f32x4*)(outv + i8) = r0;
    *(f32x4*)(outv + i8 + 4) = r1;
}

extern "C" void kernel_launch(void* const* d_in, const int* in_sizes, int n_in,
                              void* d_out, int out_size, void* d_ws, size_t ws_size,
                              hipStream_t stream) {
    (void)in_sizes; (void)n_in; (void)out_size; (void)ws_size;
    const float* x   = (const float*)d_in[0];
    const int*   ei  = (const int*)d_in[1];
    const float* W1l = (const float*)d_in[2];
    const float* b1  = (const float*)d_in[3];
    const float* W1r = (const float*)d_in[4];
    const float* g1  = (const float*)d_in[5];
    const float* bt1 = (const float*)d_in[6];
    const float* W2l = (const float*)d_in[7];
    const float* b2  = (const float*)d_in[8];
    const float* W2r = (const float*)d_in[9];
    const float* g2  = (const float*)d_in[10];
    const float* bt2 = (const float*)d_in[11];
    float* out = (float*)d_out;

    const int* esrc = ei;
    const int* edst = ei + N_EDGES;

    char* ws = (char*)d_ws;
    size_t off = 0;
    auto alloc = [&](size_t bytes) { size_t p = off; off = (off + bytes + 255) & ~(size_t)255; return p; };
    float* stats1  = (float*)(ws + alloc(4096 * 4));   // 8 banks x 512 (sum@+col, sumsq@+256+col)
    float* stats2  = (float*)(ws + alloc(4096 * 4));
    int*   bcnt    = (int*)  (ws + alloc((size_t)NBKT * 16 * 4));  // 1 counter / 64B line
    size_t zero_bytes = off;                       // everything above must be zeroed
    unsigned* bucket = (unsigned*)(ws + alloc((size_t)NBKT * CAP * 4));
    u16*   col_srt = (u16*)  (ws + alloc((size_t)NBKT * CAP * 2));
    u16*   hdr     = (u16*)  (ws + alloc((size_t)NBKT * 32 * 2));
    u16*   xh      = (u16*)  (ws + alloc((size_t)N_NODES * DIM * 2));
    u8*    xf8     = (u8*)   (ws + alloc((size_t)N_NODES * DIM));
    u16*   hb1     = (u16*)  (ws + alloc((size_t)N_NODES * DIM * 2));  // raw h1 bf16
    u8*    h1f8    = (u8*)   (ws + alloc((size_t)N_NODES * DIM));     // raw h1 fp8
    u16*   hb2     = (u16*)  (ws + alloc((size_t)N_NODES * DIM * 2));  // raw h2 bf16
    u16*   Bp1h    = (u16*)  (ws + alloc(256 * 128 * 2));
    u16*   Bp2h    = (u16*)  (ws + alloc(256 * 128 * 2));

    hipMemsetAsync(ws, 0, zero_bytes, stream);

    const int AGB = N_NODES / 16;                    // 3125 exact
    const int EWB4 = (int)(((long)N_NODES * DIM) / 1024);  // 6250 exact
    const int EWB8 = (int)(((long)N_NODES * DIM) / 2048);  // 3125 exact
    const int EDGB = (N_EDGES + 1023) / 1024;        // 782 (4 edges/thread)
    const int PREPB = 32 + EWB4 + EDGB;              // pack + split + bucket append

    // prep: pack both B + split x (bf16 + fp8) + single-pass edge bucketing
    k_prep<<<PREPB, 256, 0, stream>>>(W1l, W1r, Bp1h, W2l, W2r, Bp2h, x, xh, xf8,
                                      esrc, edst, bcnt, bucket, EWB4);

    // per-group counting sort -> col_srt + hdr
    k_sort<<<NBKT, 256, 0, stream>>>(bcnt, bucket, col_srt, hdr);

    // stage 1: fused agg+gemm on x (fp8 gather, bf16 root); writes h1 bf16 + fp8
    k_ag<0, 1><<<AGB, 256, 0, stream>>>(xf8, xh, hdr, col_srt, Bp1h, b1,
                                        stats1, g1, bt1, hb1, h1f8, stats1);

    // stage 2: fused agg+gemm on h1 with BN+relu at operand load (coeffs from stats1)
    k_ag<1, 0><<<AGB, 256, 0, stream>>>(h1f8, hb1, hdr, col_srt, Bp2h, b2,
                                        stats1, g1, bt1, hb2, h1f8, stats2);

    // epilogue: out = relu(bn(h2) + x), coeffs from stats2
    k_bn_add_relu<<<EWB8, 256, 0, stream>>>(hb2, stats2, g2, bt2, x, out);
}

// Round 5
// 229.022 us; speedup vs baseline: 1.4818x; 1.0159x over previous
//
#include <hip/hip_runtime.h>

typedef unsigned short u16;
typedef unsigned char u8;
typedef __attribute__((ext_vector_type(8))) short short8;
typedef __attribute__((ext_vector_type(2))) float f32x2;
typedef __attribute__((ext_vector_type(4))) float f32x4;
typedef __attribute__((ext_vector_type(4))) int i32x4;
typedef __attribute__((ext_vector_type(4))) unsigned short us4;
typedef __attribute__((ext_vector_type(8))) unsigned short us8;
typedef __attribute__((ext_vector_type(4))) unsigned int u32x4;

#define N_NODES 50000
#define N_EDGES 800000
#define DIM 128
#define NINV (1.0f / 50000.0f)
#define SROW 136      /* LDS row stride (u16) */
#define NBKT 3125     /* node groups of 16: 50000/16 */
#define CAP 512       /* merged-group capacity; mean 256, P(overflow) ~ e^-99 */
#define SUBCAP 96     /* per-XCD sub-bucket capacity; mean 32, P(overflow) ~ 1e-15 */

__device__ __forceinline__ float bf2f(u16 u) {
    union { unsigned int i; float f; } v; v.i = ((unsigned int)u) << 16; return v.f;
}
__device__ __forceinline__ u16 f2bf(float f) {
    union { float f; unsigned int i; } v; v.f = f;
    return (u16)((v.i + 0x7FFFu + ((v.i >> 16) & 1u)) >> 16);
}

// ---------------- prep: pack B1/B2, split x, single-pass XCD-private edge bucketing ----
// blocks 0..15: pack B1; 16..31: pack B2; 32..32+splitB-1: split x;
// rest (782): one pass, 4 edges/thread; append (src<<4 | dst&15) into sub-bucket
// region (blockIdx&7). Blocks round-robin to XCDs, so each region's counter/data
// lines are owned by one XCD's L2: local atomics, single write-back per line.
__global__ __launch_bounds__(256) void k_prep(
        const float* __restrict__ W1l, const float* __restrict__ W1r, u16* __restrict__ Bp1,
        const float* __restrict__ W2l, const float* __restrict__ W2r, u16* __restrict__ Bp2,
        const float* __restrict__ x, u16* __restrict__ xh, u8* __restrict__ xf8,
        const int* __restrict__ esrc, const int* __restrict__ edst,
        int* __restrict__ bcnt, unsigned* __restrict__ bucket, int splitB) {
    int b = blockIdx.x;
    if (b < 32) {
        const float* Wl = (b < 16) ? W1l : W2l;
        const float* Wr = (b < 16) ? W1r : W2r;
        u16* Bp = (b < 16) ? Bp1 : Bp2;
        int idx = (b & 15) * 256 + threadIdx.x;      // 0..4095
        int lane = idx & 63;
        int kc = (idx >> 6) & 7;
        int nt = idx >> 9;
        int q = lane >> 4, nn = lane & 15;
        int col = nt * 16 + nn;
        #pragma unroll
        for (int j = 0; j < 8; ++j) {
            int k = kc * 32 + q * 8 + j;
            float v = (k < 128) ? Wl[k * 128 + col] : Wr[(k - 128) * 128 + col];
            Bp[(long)idx * 8 + j] = f2bf(v);
        }
    } else if (b < 32 + splitB) {
        long i4 = ((long)(b - 32) * 256 + threadIdx.x) * 4;
        f32x4 v = *(const f32x4*)(x + i4);
        us4 h;
        #pragma unroll
        for (int j = 0; j < 4; ++j) h[j] = f2bf(v[j]);
        *(us4*)(xh + i4) = h;
        int p = __builtin_amdgcn_cvt_pk_fp8_f32(v[0], v[1], 0, false);
        p = __builtin_amdgcn_cvt_pk_fp8_f32(v[2], v[3], p, true);
        *(int*)(xf8 + i4) = p;
    } else {
        int hb = b - 32 - splitB;           // 0..781, each owns a 1024-edge chunk
        int sub = b & 7;                    // XCD-aligned sub-bucket region
        int e4 = hb * 1024 + threadIdx.x * 4;
        if (e4 < N_EDGES) {   // N_EDGES % 4 == 0, so full int4 is in-range
            i32x4 d4 = *(const i32x4*)(edst + e4);
            i32x4 s4 = *(const i32x4*)(esrc + e4);
            #pragma unroll
            for (int j = 0; j < 4; ++j) {
                int d = d4[j];
                int key = d >> 4;
                int slot = sub * NBKT + key;
                int pos = atomicAdd(&bcnt[slot << 4], 1);
                if (pos < SUBCAP)
                    bucket[(long)slot * SUBCAP + pos] = ((unsigned)s4[j] << 4) | (unsigned)(d & 15);
            }
        }
    }
}

// ---------------- per-group 8-way merge + counting sort -> col_srt + header ----------
// hdr[bid*32 + i]   = group-local start of node i's edges (u16)
// hdr[bid*32+16+i]  = degree of node i (u16)
__global__ __launch_bounds__(256) void k_sort(
        const int* __restrict__ bcnt, const unsigned* __restrict__ bucket,
        u16* __restrict__ col_srt, u16* __restrict__ hdr) {
    __shared__ int sHist[16], sStart[16], sCur[16];
    __shared__ u16 sSort[CAP];
    int tid = threadIdx.x;
    int bid = blockIdx.x;
    unsigned ent[8];
    int cnt[8];
    #pragma unroll
    for (int p = 0; p < 8; ++p) {
        int slot = p * NBKT + bid;
        int c = bcnt[slot << 4];
        if (c > SUBCAP) c = SUBCAP;
        cnt[p] = c;
        ent[p] = (tid < c) ? bucket[(long)slot * SUBCAP + tid] : 0u;
    }
    if (tid < 16) sHist[tid] = 0;
    __syncthreads();
    #pragma unroll
    for (int p = 0; p < 8; ++p)
        if (tid < cnt[p]) atomicAdd(&sHist[ent[p] & 15u], 1);
    __syncthreads();
    if (tid == 0) {
        int acc = 0;
        #pragma unroll
        for (int i = 0; i < 16; ++i) { sStart[i] = acc; sCur[i] = acc; acc += sHist[i]; }
    }
    __syncthreads();
    #pragma unroll
    for (int p = 0; p < 8; ++p)
        if (tid < cnt[p]) {
            int pos = atomicAdd(&sCur[ent[p] & 15u], 1);
            if (pos < CAP) sSort[pos] = (u16)(ent[p] >> 4);
        }
    __syncthreads();
    int tot = sStart[15] + sHist[15]; if (tot > CAP) tot = CAP;
    if (tid < tot) col_srt[(long)bid * CAP + tid] = sSort[tid];
    if (tid + 256 < tot) col_srt[(long)bid * CAP + tid + 256] = sSort[tid + 256];
    if (tid < 16) {
        hdr[bid * 32 + tid] = (u16)sStart[tid];
        hdr[bid * 32 + 16 + tid] = (u16)sHist[tid];
    }
}

// decode 16 fp8 + (optional BN+relu) + accumulate
template<int BN>
__device__ __forceinline__ void acc_row16(u32x4 w,
        float sum[16], const float av[16], const float ov[16]) {
    float t[16];
    f32x2 p;
    #pragma unroll
    for (int h = 0; h < 4; ++h) {
        p = __builtin_amdgcn_cvt_pk_f32_fp8((int)w[h], false); t[h*4+0] = p[0]; t[h*4+1] = p[1];
        p = __builtin_amdgcn_cvt_pk_f32_fp8((int)w[h], true);  t[h*4+2] = p[0]; t[h*4+3] = p[1];
    }
    #pragma unroll
    for (int k = 0; k < 16; ++k) {
        float v = t[k];
        if (BN) { v = v * av[k] + ov[k]; v = v > 0.f ? v : 0.f; }
        sum[k] += v;
    }
}

// ---------------- fused AGG + GEMM + BN stats (round-0 structure, 256 threads) ----------------
template<int BN, int W8>
__global__ __launch_bounds__(256) void k_ag(
        const u8* __restrict__ fq, const u16* __restrict__ fh,
        const u16* __restrict__ hdr, const u16* __restrict__ col_srt,
        const u16* __restrict__ Bph, const float* __restrict__ bias,
        const float* __restrict__ statsPrev, const float* __restrict__ gP,
        const float* __restrict__ btP,
        u16* __restrict__ h16, u8* __restrict__ h8, float* __restrict__ stats) {
    __shared__ u16 sA[16 * SROW];
    __shared__ float acS[256];
    int tid = threadIdx.x;
    long nodebase = (long)blockIdx.x * 16;       // 3125*16 == 50000 exact

    if (BN) {
        if (tid < 128) {
            float s = 0.f, qq = 0.f;
            #pragma unroll
            for (int b = 0; b < 8; ++b) {
                s  += statsPrev[b * 512 + tid];
                qq += statsPrev[b * 512 + 256 + tid];
            }
            float mu = s * NINV;
            float var = qq * NINV - mu * mu;
            float a = gP[tid] * rsqrtf(var + 1e-5f);
            acS[tid] = a;
            acS[128 + tid] = btP[tid] - mu * a;
        }
        __syncthreads();
    }

    // ---- phase 1: gather-mean (fp8, 16B/lane, even/odd edge split) ----
    {
        int grp = tid >> 4;          // node 0..15
        int g   = tid & 15;
        int sub = g >> 3;            // 0: even edges, 1: odd edges
        int gl  = g & 7;
        int d16 = gl * 16;           // dim base
        const u16* cs = col_srt + (long)blockIdx.x * CAP;
        int st  = hdr[blockIdx.x * 32 + grp];
        int deg = hdr[blockIdx.x * 32 + 16 + grp];
        int s = st, e = st + deg;
        float av[16], ov[16];
        if (BN) {
            #pragma unroll
            for (int k = 0; k < 16; ++k) { av[k] = acS[d16 + k]; ov[k] = acS[128 + d16 + k]; }
        }
        float sum[16];
        #pragma unroll
        for (int k = 0; k < 16; ++k) sum[k] = 0.f;
        int j = s + sub;
        for (; j + 6 < e; j += 8) {
            int i0 = cs[j], i1 = cs[j + 2], i2 = cs[j + 4], i3 = cs[j + 6];
            u32x4 w0 = *(const u32x4*)(fq + (long)i0 * DIM + d16);
            u32x4 w1 = *(const u32x4*)(fq + (long)i1 * DIM + d16);
            u32x4 w2 = *(const u32x4*)(fq + (long)i2 * DIM + d16);
            u32x4 w3 = *(const u32x4*)(fq + (long)i3 * DIM + d16);
            acc_row16<BN>(w0, sum, av, ov);
            acc_row16<BN>(w1, sum, av, ov);
            acc_row16<BN>(w2, sum, av, ov);
            acc_row16<BN>(w3, sum, av, ov);
        }
        for (; j < e; j += 2) {
            int i0 = cs[j];
            u32x4 w0 = *(const u32x4*)(fq + (long)i0 * DIM + d16);
            acc_row16<BN>(w0, sum, av, ov);
        }
        // combine even/odd halves
        #pragma unroll
        for (int k = 0; k < 16; ++k) sum[k] += __shfl_xor(sum[k], 8);
        if (sub == 0) {
            float dn = (deg > 0) ? 1.f / (float)deg : 1.f;
            us8 r0, r1;
            #pragma unroll
            for (int k = 0; k < 8; ++k) {
                r0[k] = f2bf(sum[k] * dn);
                r1[k] = f2bf(sum[8 + k] * dn);
            }
            *(us8*)(sA + grp * SROW + d16) = r0;
            *(us8*)(sA + grp * SROW + d16 + 8) = r1;
        }
    }
    __syncthreads();

    // ---- phase 2: MFMA ----
    int cg = tid >> 6, lane = tid & 63;
    int q = lane >> 4, nn = lane & 15;
    long rc = nodebase + nn;

    short8 ah[8];
    #pragma unroll
    for (int kc = 0; kc < 4; ++kc)
        ah[kc] = *(const short8*)(sA + nn * SROW + kc * 32 + q * 8);
    #pragma unroll
    for (int kc = 0; kc < 4; ++kc) {
        int ko = kc * 32 + q * 8;
        us8 rv = *(const us8*)(fh + rc * DIM + ko);
        short8 t;
        if (BN) {
            #pragma unroll
            for (int j = 0; j < 8; ++j) {
                float v = bf2f(rv[j]) * acS[ko + j] + acS[128 + ko + j];
                t[j] = (short)f2bf(v > 0.f ? v : 0.f);
            }
        } else {
            #pragma unroll
            for (int j = 0; j < 8; ++j) t[j] = (short)rv[j];
        }
        ah[4 + kc] = t;
    }

    f32x4 acc[2];
    acc[0] = (f32x4){0.f, 0.f, 0.f, 0.f};
    acc[1] = (f32x4){0.f, 0.f, 0.f, 0.f};

    #pragma unroll
    for (int kc = 0; kc < 8; ++kc) {
        #pragma unroll
        for (int nt = 0; nt < 2; ++nt) {
            int ntg = cg * 2 + nt;
            short8 bh = *(const short8*)(Bph + (((ntg * 8 + kc) * 64 + lane) << 3));
            acc[nt] = __builtin_amdgcn_mfma_f32_16x16x32_bf16(ah[kc], bh, acc[nt], 0, 0, 0);
        }
    }

    int bank = blockIdx.x & 7;
    #pragma unroll
    for (int nt = 0; nt < 2; ++nt) {
        int col = cg * 32 + nt * 16 + nn;
        float bv = bias[col];
        float ps = 0.f, pq = 0.f;
        #pragma unroll
        for (int r = 0; r < 4; ++r) {
            float v = acc[nt][r] + bv;
            long idx = (nodebase + q * 4 + r) * DIM + col;
            h16[idx] = f2bf(v);
            if (W8) {
                int pb = __builtin_amdgcn_cvt_pk_fp8_f32(v, v, 0, false);
                h8[idx] = (u8)(pb & 0xff);
            }
            ps += v; pq += v * v;
        }
        ps += __shfl_xor(ps, 16);
        ps += __shfl_xor(ps, 32);
        pq += __shfl_xor(pq, 16);
        pq += __shfl_xor(pq, 32);
        if (q == 0) {
            atomicAdd(&stats[bank * 512 + col], ps);
            atomicAdd(&stats[bank * 512 + 256 + col], pq);
        }
    }
}

// out = relu(bn(h)+x); coeffs computed in-block from banked stats
__global__ __launch_bounds__(256) void k_bn_add_relu(
        const u16* __restrict__ h, const float* __restrict__ stats,
        const float* __restrict__ g, const float* __restrict__ bt,
        const float* __restrict__ x, float* __restrict__ outv) {
    __shared__ float acS[256];
    int tid = threadIdx.x;
    if (tid < 128) {
        float s = 0.f, qq = 0.f;
        #pragma unroll
        for (int b = 0; b < 8; ++b) {
            s  += stats[b * 512 + tid];
            qq += stats[b * 512 + 256 + tid];
        }
        float mu = s * NINV;
        float var = qq * NINV - mu * mu;
        float a = g[tid] * rsqrtf(var + 1e-5f);
        acS[tid] = a;
        acS[128 + tid] = bt[tid] - mu * a;
    }
    __syncthreads();
    long i8 = ((long)blockIdx.x * 256 + tid) * 8;
    int c = (int)(i8 & 127);
    us8 hv = *(const us8*)(h + i8);
    f32x4 x0 = *(const f32x4*)(x + i8);
    f32x4 x1 = *(const f32x4*)(x + i8 + 4);
    f32x4 r0, r1;
    #pragma unroll
    for (int j = 0; j < 4; ++j) {
        float v = bf2f(hv[j]) * acS[c + j] + acS[128 + c + j] + x0[j];
        r0[j] = v > 0.f ? v : 0.f;
        float w = bf2f(hv[4 + j]) * acS[c + 4 + j] + acS[128 + c + 4 + j] + x1[j];
        r1[j] = w > 0.f ? w : 0.f;
    }
    *(f32x4*)(outv + i8) = r0;
    *(f32x4*)(outv + i8 + 4) = r1;
}

extern "C" void kernel_launch(void* const* d_in, const int* in_sizes, int n_in,
                              void* d_out, int out_size, void* d_ws, size_t ws_size,
                              hipStream_t stream) {
    (void)in_sizes; (void)n_in; (void)out_size; (void)ws_size;
    const float* x   = (const float*)d_in[0];
    const int*   ei  = (const int*)d_in[1];
    const float* W1l = (const float*)d_in[2];
    const float* b1  = (const float*)d_in[3];
    const float* W1r = (const float*)d_in[4];
    const float* g1  = (const float*)d_in[5];
    const float* bt1 = (const float*)d_in[6];
    const float* W2l = (const float*)d_in[7];
    const float* b2  = (const float*)d_in[8];
    const float* W2r = (const float*)d_in[9];
    const float* g2  = (const float*)d_in[10];
    const float* bt2 = (const float*)d_in[11];
    float* out = (float*)d_out;

    const int* esrc = ei;
    const int* edst = ei + N_EDGES;

    char* ws = (char*)d_ws;
    size_t off = 0;
    auto alloc = [&](size_t bytes) { size_t p = off; off = (off + bytes + 255) & ~(size_t)255; return p; };
    float* stats1  = (float*)(ws + alloc(4096 * 4));   // 8 banks x 512 (sum@+col, sumsq@+256+col)
    float* stats2  = (float*)(ws + alloc(4096 * 4));
    int*   bcnt    = (int*)  (ws + alloc((size_t)8 * NBKT * 16 * 4));  // 8 regions, 1 counter/64B line
    size_t zero_bytes = off;                       // everything above must be zeroed
    unsigned* bucket = (unsigned*)(ws + alloc((size_t)8 * NBKT * SUBCAP * 4));
    u16*   col_srt = (u16*)  (ws + alloc((size_t)NBKT * CAP * 2));
    u16*   hdr     = (u16*)  (ws + alloc((size_t)NBKT * 32 * 2));
    u16*   xh      = (u16*)  (ws + alloc((size_t)N_NODES * DIM * 2));
    u8*    xf8     = (u8*)   (ws + alloc((size_t)N_NODES * DIM));
    u16*   hb1     = (u16*)  (ws + alloc((size_t)N_NODES * DIM * 2));  // raw h1 bf16
    u8*    h1f8    = (u8*)   (ws + alloc((size_t)N_NODES * DIM));     // raw h1 fp8
    u16*   hb2     = (u16*)  (ws + alloc((size_t)N_NODES * DIM * 2));  // raw h2 bf16
    u16*   Bp1h    = (u16*)  (ws + alloc(256 * 128 * 2));
    u16*   Bp2h    = (u16*)  (ws + alloc(256 * 128 * 2));

    hipMemsetAsync(ws, 0, zero_bytes, stream);

    const int AGB = N_NODES / 16;                    // 3125 exact
    const int EWB4 = (int)(((long)N_NODES * DIM) / 1024);  // 6250 exact
    const int EWB8 = (int)(((long)N_NODES * DIM) / 2048);  // 3125 exact
    const int EDGB = (N_EDGES + 1023) / 1024;        // 782 (4 edges/thread)
    const int PREPB = 32 + EWB4 + EDGB;              // pack + split + bucket append

    // prep: pack both B + split x (bf16 + fp8) + single-pass XCD-private bucketing
    k_prep<<<PREPB, 256, 0, stream>>>(W1l, W1r, Bp1h, W2l, W2r, Bp2h, x, xh, xf8,
                                      esrc, edst, bcnt, bucket, EWB4);

    // per-group 8-way merge + counting sort -> col_srt + hdr
    k_sort<<<NBKT, 256, 0, stream>>>(bcnt, bucket, col_srt, hdr);

    // stage 1: fused agg+gemm on x (fp8 gather, bf16 root); writes h1 bf16 + fp8
    k_ag<0, 1><<<AGB, 256, 0, stream>>>(xf8, xh, hdr, col_srt, Bp1h, b1,
                                        stats1, g1, bt1, hb1, h1f8, stats1);

    // stage 2: fused agg+gemm on h1 with BN+relu at operand load (coeffs from stats1)
    k_ag<1, 0><<<AGB, 256, 0, stream>>>(h1f8, hb1, hdr, col_srt, Bp2h, b2,
                                        stats1, g1, bt1, hb2, h1f8, stats2);

    // epilogue: out = relu(bn(h2) + x), coeffs from stats2
    k_bn_add_relu<<<EWB8, 256, 0, stream>>>(hb2, stats2, g2, bt2, x, out);
}

// Round 6
// 207.144 us; speedup vs baseline: 1.6383x; 1.1056x over previous
//
#include <hip/hip_runtime.h>

typedef unsigned short u16;
typedef unsigned char u8;
typedef __attribute__((ext_vector_type(8))) short short8;
typedef __attribute__((ext_vector_type(2))) float f32x2;
typedef __attribute__((ext_vector_type(4))) float f32x4;
typedef __attribute__((ext_vector_type(4))) int i32x4;
typedef __attribute__((ext_vector_type(4))) unsigned short us4;
typedef __attribute__((ext_vector_type(8))) unsigned short us8;
typedef __attribute__((ext_vector_type(4))) unsigned int u32x4;

#define N_NODES 50000
#define N_EDGES 800000
#define DIM 128
#define NINV (1.0f / 50000.0f)
#define SROW 136      /* LDS row stride (u16) */
#define NBKT 3125     /* node groups of 16: 50000/16 */
#define CAP 512       /* per-group capacity; mean 256, P(overflow) ~ e^-99 */
#define SUPN 800      /* nodes per superkey (50 groups) */
#define NSUP 63       /* ceil(50000/800); last superkey has 400 nodes */
#define SEGCAP 16384  /* segment entries per superkey; mean 12800, ~31 sigma margin */

__device__ __forceinline__ float bf2f(u16 u) {
    union { unsigned int i; float f; } v; v.i = ((unsigned int)u) << 16; return v.f;
}
__device__ __forceinline__ u16 f2bf(float f) {
    union { float f; unsigned int i; } v; v.f = f;
    return (u16)((v.i + 0x7FFFu + ((v.i >> 16) & 1u)) >> 16);
}

// ---------------- prep: pack B1/B2, split x, LDS-binned segmented edge bucketing ----
// blocks 0..15: pack B1; 16..31: pack B2; 32..32+splitB-1: split x;
// rest (782): 1024 edges/block. LDS-bin into 63 superkeys (hist+scan+scatter),
// ONE segment-reserve global atomic per non-empty (block, superkey) (~50K total,
// vs 800K per-edge atomics), then coalesced run-writes into per-superkey segments.
// Entry = src<<10 | (dst - superkey*800)  (16+10 bits).
__global__ __launch_bounds__(256) void k_prep(
        const float* __restrict__ W1l, const float* __restrict__ W1r, u16* __restrict__ Bp1,
        const float* __restrict__ W2l, const float* __restrict__ W2r, u16* __restrict__ Bp2,
        const float* __restrict__ x, u16* __restrict__ xh, u8* __restrict__ xf8,
        const int* __restrict__ esrc, const int* __restrict__ edst,
        int* __restrict__ segCnt, unsigned* __restrict__ segBuf, int splitB) {
    int b = blockIdx.x;
    if (b < 32) {
        const float* Wl = (b < 16) ? W1l : W2l;
        const float* Wr = (b < 16) ? W1r : W2r;
        u16* Bp = (b < 16) ? Bp1 : Bp2;
        int idx = (b & 15) * 256 + threadIdx.x;      // 0..4095
        int lane = idx & 63;
        int kc = (idx >> 6) & 7;
        int nt = idx >> 9;
        int q = lane >> 4, nn = lane & 15;
        int col = nt * 16 + nn;
        #pragma unroll
        for (int j = 0; j < 8; ++j) {
            int k = kc * 32 + q * 8 + j;
            float v = (k < 128) ? Wl[k * 128 + col] : Wr[(k - 128) * 128 + col];
            Bp[(long)idx * 8 + j] = f2bf(v);
        }
    } else if (b < 32 + splitB) {
        long i4 = ((long)(b - 32) * 256 + threadIdx.x) * 4;
        f32x4 v = *(const f32x4*)(x + i4);
        us4 h;
        #pragma unroll
        for (int j = 0; j < 4; ++j) h[j] = f2bf(v[j]);
        *(us4*)(xh + i4) = h;
        int p = __builtin_amdgcn_cvt_pk_fp8_f32(v[0], v[1], 0, false);
        p = __builtin_amdgcn_cvt_pk_fp8_f32(v[2], v[3], p, true);
        *(int*)(xf8 + i4) = p;
    } else {
        __shared__ int sHistB[64], sScanB[64], sCurB[64], sBaseB[64];
        __shared__ unsigned sStage[1024];
        __shared__ u8 sBinOf[1024];
        int tid = threadIdx.x;
        int hb = b - 32 - splitB;
        int e4 = hb * 1024 + tid * 4;
        bool val = e4 < N_EDGES;       // N_EDGES % 4 == 0: all-or-nothing per thread
        if (tid < 64) sHistB[tid] = 0;
        __syncthreads();
        unsigned ent[4]; int bin[4];
        if (val) {
            i32x4 d4 = *(const i32x4*)(edst + e4);
            i32x4 s4 = *(const i32x4*)(esrc + e4);
            #pragma unroll
            for (int j = 0; j < 4; ++j) {
                unsigned dd = (unsigned)d4[j];
                int bi = (int)(dd / 800u);
                bin[j] = bi;
                ent[j] = ((unsigned)s4[j] << 10) | (dd - (unsigned)bi * 800u);
                atomicAdd(&sHistB[bi], 1);
            }
        }
        __syncthreads();
        if (tid == 0) {
            int acc = 0;
            #pragma unroll
            for (int i = 0; i < 64; ++i) { sScanB[i] = acc; sCurB[i] = acc; acc += sHistB[i]; }
        }
        __syncthreads();
        if (val) {
            #pragma unroll
            for (int j = 0; j < 4; ++j) {
                int p = atomicAdd(&sCurB[bin[j]], 1);
                sStage[p] = ent[j];
                sBinOf[p] = (u8)bin[j];
            }
        }
        __syncthreads();
        if (tid < 64) {
            int c = sHistB[tid];
            sBaseB[tid] = c ? atomicAdd(&segCnt[tid << 4], c) : 0;
        }
        __syncthreads();
        int tcount = sScanB[63] + sHistB[63];
        for (int p = tid; p < tcount; p += 256) {
            int bn = sBinOf[p];
            long ofs = (long)sBaseB[bn] + (p - sScanB[bn]);
            if (ofs < SEGCAP)
                segBuf[(long)bn * SEGCAP + ofs] = sStage[p];
        }
    }
}

// ---------------- per-superkey counting sort -> col_srt (group-CAP layout) + hdr ----
// 63 blocks x 512 threads; entries held in registers (32/thread), LDS hist over 800
// node bins, per-group-of-16 scan, LDS-atomic rank, direct scatter to col_srt.
// hdr[g*32 + i] = group-local start of node i; hdr[g*32+16+i] = degree (clamped).
__global__ __launch_bounds__(512) void k_sort(
        const int* __restrict__ segCnt, const unsigned* __restrict__ segBuf,
        u16* __restrict__ col_srt, u16* __restrict__ hdr) {
    __shared__ int sHist[SUPN], sStart[SUPN], sCur[SUPN];
    int tid = threadIdx.x;
    int s = blockIdx.x;
    int nnodes = N_NODES - s * SUPN; if (nnodes > SUPN) nnodes = SUPN;
    int ngroups = nnodes >> 4;
    int n = segCnt[s << 4]; if (n > SEGCAP) n = SEGCAP;
    for (int i = tid; i < SUPN; i += 512) { sHist[i] = 0; sCur[i] = 0; }
    __syncthreads();
    const unsigned* seg = segBuf + (long)s * SEGCAP;
    unsigned ent[32];
    #pragma unroll
    for (int i = 0; i < 32; ++i) {
        int idx = i * 512 + tid;                 // coalesced
        ent[i] = (idx < n) ? seg[idx] : 0xFFFFFFFFu;
    }
    #pragma unroll
    for (int i = 0; i < 32; ++i)
        if (ent[i] != 0xFFFFFFFFu) atomicAdd(&sHist[ent[i] & 1023u], 1);
    __syncthreads();
    if (tid < ngroups) {
        int base = 0;
        int gb = (s * 50 + tid) * 32;
        #pragma unroll
        for (int i = 0; i < 16; ++i) {
            int node = tid * 16 + i;
            int d = sHist[node];
            int st_c = base < CAP ? base : CAP;
            int en_c = base + d < CAP ? base + d : CAP;
            sStart[node] = base;
            hdr[gb + i] = (u16)st_c;
            hdr[gb + 16 + i] = (u16)(en_c - st_c);
            base += d;
        }
    }
    __syncthreads();
    #pragma unroll
    for (int i = 0; i < 32; ++i) {
        unsigned e = ent[i];
        if (e != 0xFFFFFFFFu) {
            int node = (int)(e & 1023u);
            int pos = atomicAdd(&sCur[node], 1);
            int ofs = sStart[node] + pos;
            if (ofs < CAP)
                col_srt[(long)(s * 50 + (node >> 4)) * CAP + ofs] = (u16)(e >> 10);
        }
    }
}

// decode 16 fp8 + (optional BN+relu) + accumulate
template<int BN>
__device__ __forceinline__ void acc_row16(u32x4 w,
        float sum[16], const float av[16], const float ov[16]) {
    float t[16];
    f32x2 p;
    #pragma unroll
    for (int h = 0; h < 4; ++h) {
        p = __builtin_amdgcn_cvt_pk_f32_fp8((int)w[h], false); t[h*4+0] = p[0]; t[h*4+1] = p[1];
        p = __builtin_amdgcn_cvt_pk_f32_fp8((int)w[h], true);  t[h*4+2] = p[0]; t[h*4+3] = p[1];
    }
    #pragma unroll
    for (int k = 0; k < 16; ++k) {
        float v = t[k];
        if (BN) { v = v * av[k] + ov[k]; v = v > 0.f ? v : 0.f; }
        sum[k] += v;
    }
}

// ---------------- fused AGG + GEMM + BN stats (256 threads) ----------------
// index list staged in LDS (sIdx) so the gather chain is LDS->global, not L2->global.
template<int BN, int W8>
__global__ __launch_bounds__(256) void k_ag(
        const u8* __restrict__ fq, const u16* __restrict__ fh,
        const u16* __restrict__ hdr, const u16* __restrict__ col_srt,
        const u16* __restrict__ Bph, const float* __restrict__ bias,
        const float* __restrict__ statsPrev, const float* __restrict__ gP,
        const float* __restrict__ btP,
        u16* __restrict__ h16, u8* __restrict__ h8, float* __restrict__ stats) {
    __shared__ u16 sA[16 * SROW];
    __shared__ float acS[256];
    __shared__ __align__(16) u16 sIdx[CAP];
    int tid = threadIdx.x;
    long nodebase = (long)blockIdx.x * 16;       // 3125*16 == 50000 exact

    // stage sorted index list (1KB) into LDS
    if (tid < 64)
        *(us8*)(sIdx + tid * 8) = *(const us8*)(col_srt + (long)blockIdx.x * CAP + tid * 8);

    if (BN) {
        if (tid < 128) {
            float s = 0.f, qq = 0.f;
            #pragma unroll
            for (int b = 0; b < 8; ++b) {
                s  += statsPrev[b * 512 + tid];
                qq += statsPrev[b * 512 + 256 + tid];
            }
            float mu = s * NINV;
            float var = qq * NINV - mu * mu;
            float a = gP[tid] * rsqrtf(var + 1e-5f);
            acS[tid] = a;
            acS[128 + tid] = btP[tid] - mu * a;
        }
    }
    __syncthreads();

    // ---- phase 1: gather-mean (fp8, 16B/lane, even/odd edge split) ----
    {
        int grp = tid >> 4;          // node 0..15
        int g   = tid & 15;
        int sub = g >> 3;            // 0: even edges, 1: odd edges
        int gl  = g & 7;
        int d16 = gl * 16;           // dim base
        int st  = hdr[blockIdx.x * 32 + grp];
        int deg = hdr[blockIdx.x * 32 + 16 + grp];
        int s = st, e = st + deg;
        float av[16], ov[16];
        if (BN) {
            #pragma unroll
            for (int k = 0; k < 16; ++k) { av[k] = acS[d16 + k]; ov[k] = acS[128 + d16 + k]; }
        }
        float sum[16];
        #pragma unroll
        for (int k = 0; k < 16; ++k) sum[k] = 0.f;
        int j = s + sub;
        for (; j + 6 < e; j += 8) {
            int i0 = sIdx[j], i1 = sIdx[j + 2], i2 = sIdx[j + 4], i3 = sIdx[j + 6];
            u32x4 w0 = *(const u32x4*)(fq + (long)i0 * DIM + d16);
            u32x4 w1 = *(const u32x4*)(fq + (long)i1 * DIM + d16);
            u32x4 w2 = *(const u32x4*)(fq + (long)i2 * DIM + d16);
            u32x4 w3 = *(const u32x4*)(fq + (long)i3 * DIM + d16);
            acc_row16<BN>(w0, sum, av, ov);
            acc_row16<BN>(w1, sum, av, ov);
            acc_row16<BN>(w2, sum, av, ov);
            acc_row16<BN>(w3, sum, av, ov);
        }
        for (; j < e; j += 2) {
            int i0 = sIdx[j];
            u32x4 w0 = *(const u32x4*)(fq + (long)i0 * DIM + d16);
            acc_row16<BN>(w0, sum, av, ov);
        }
        // combine even/odd halves
        #pragma unroll
        for (int k = 0; k < 16; ++k) sum[k] += __shfl_xor(sum[k], 8);
        if (sub == 0) {
            float dn = (deg > 0) ? 1.f / (float)deg : 1.f;
            us8 r0, r1;
            #pragma unroll
            for (int k = 0; k < 8; ++k) {
                r0[k] = f2bf(sum[k] * dn);
                r1[k] = f2bf(sum[8 + k] * dn);
            }
            *(us8*)(sA + grp * SROW + d16) = r0;
            *(us8*)(sA + grp * SROW + d16 + 8) = r1;
        }
    }
    __syncthreads();

    // ---- phase 2: MFMA ----
    int cg = tid >> 6, lane = tid & 63;
    int q = lane >> 4, nn = lane & 15;
    long rc = nodebase + nn;

    short8 ah[8];
    #pragma unroll
    for (int kc = 0; kc < 4; ++kc)
        ah[kc] = *(const short8*)(sA + nn * SROW + kc * 32 + q * 8);
    #pragma unroll
    for (int kc = 0; kc < 4; ++kc) {
        int ko = kc * 32 + q * 8;
        us8 rv = *(const us8*)(fh + rc * DIM + ko);
        short8 t;
        if (BN) {
            #pragma unroll
            for (int j = 0; j < 8; ++j) {
                float v = bf2f(rv[j]) * acS[ko + j] + acS[128 + ko + j];
                t[j] = (short)f2bf(v > 0.f ? v : 0.f);
            }
        } else {
            #pragma unroll
            for (int j = 0; j < 8; ++j) t[j] = (short)rv[j];
        }
        ah[4 + kc] = t;
    }

    f32x4 acc[2];
    acc[0] = (f32x4){0.f, 0.f, 0.f, 0.f};
    acc[1] = (f32x4){0.f, 0.f, 0.f, 0.f};

    #pragma unroll
    for (int kc = 0; kc < 8; ++kc) {
        #pragma unroll
        for (int nt = 0; nt < 2; ++nt) {
            int ntg = cg * 2 + nt;
            short8 bh = *(const short8*)(Bph + (((ntg * 8 + kc) * 64 + lane) << 3));
            acc[nt] = __builtin_amdgcn_mfma_f32_16x16x32_bf16(ah[kc], bh, acc[nt], 0, 0, 0);
        }
    }

    int bank = blockIdx.x & 7;
    #pragma unroll
    for (int nt = 0; nt < 2; ++nt) {
        int col = cg * 32 + nt * 16 + nn;
        float bv = bias[col];
        float ps = 0.f, pq = 0.f;
        #pragma unroll
        for (int r = 0; r < 4; ++r) {
            float v = acc[nt][r] + bv;
            long idx = (nodebase + q * 4 + r) * DIM + col;
            h16[idx] = f2bf(v);
            if (W8) {
                int pb = __builtin_amdgcn_cvt_pk_fp8_f32(v, v, 0, false);
                h8[idx] = (u8)(pb & 0xff);
            }
            ps += v; pq += v * v;
        }
        ps += __shfl_xor(ps, 16);
        ps += __shfl_xor(ps, 32);
        pq += __shfl_xor(pq, 16);
        pq += __shfl_xor(pq, 32);
        if (q == 0) {
            atomicAdd(&stats[bank * 512 + col], ps);
            atomicAdd(&stats[bank * 512 + 256 + col], pq);
        }
    }
}

// out = relu(bn(h)+x); coeffs computed in-block from banked stats
__global__ __launch_bounds__(256) void k_bn_add_relu(
        const u16* __restrict__ h, const float* __restrict__ stats,
        const float* __restrict__ g, const float* __restrict__ bt,
        const float* __restrict__ x, float* __restrict__ outv) {
    __shared__ float acS[256];
    int tid = threadIdx.x;
    if (tid < 128) {
        float s = 0.f, qq = 0.f;
        #pragma unroll
        for (int b = 0; b < 8; ++b) {
            s  += stats[b * 512 + tid];
            qq += stats[b * 512 + 256 + tid];
        }
        float mu = s * NINV;
        float var = qq * NINV - mu * mu;
        float a = g[tid] * rsqrtf(var + 1e-5f);
        acS[tid] = a;
        acS[128 + tid] = bt[tid] - mu * a;
    }
    __syncthreads();
    long i8 = ((long)blockIdx.x * 256 + tid) * 8;
    int c = (int)(i8 & 127);
    us8 hv = *(const us8*)(h + i8);
    f32x4 x0 = *(const f32x4*)(x + i8);
    f32x4 x1 = *(const f32x4*)(x + i8 + 4);
    f32x4 r0, r1;
    #pragma unroll
    for (int j = 0; j < 4; ++j) {
        float v = bf2f(hv[j]) * acS[c + j] + acS[128 + c + j] + x0[j];
        r0[j] = v > 0.f ? v : 0.f;
        float w = bf2f(hv[4 + j]) * acS[c + 4 + j] + acS[128 + c + 4 + j] + x1[j];
        r1[j] = w > 0.f ? w : 0.f;
    }
    *(f32x4*)(outv + i8) = r0;
    *(f32x4*)(outv + i8 + 4) = r1;
}

extern "C" void kernel_launch(void* const* d_in, const int* in_sizes, int n_in,
                              void* d_out, int out_size, void* d_ws, size_t ws_size,
                              hipStream_t stream) {
    (void)in_sizes; (void)n_in; (void)out_size; (void)ws_size;
    const float* x   = (const float*)d_in[0];
    const int*   ei  = (const int*)d_in[1];
    const float* W1l = (const float*)d_in[2];
    const float* b1  = (const float*)d_in[3];
    const float* W1r = (const float*)d_in[4];
    const float* g1  = (const float*)d_in[5];
    const float* bt1 = (const float*)d_in[6];
    const float* W2l = (const float*)d_in[7];
    const float* b2  = (const float*)d_in[8];
    const float* W2r = (const float*)d_in[9];
    const float* g2  = (const float*)d_in[10];
    const float* bt2 = (const float*)d_in[11];
    float* out = (float*)d_out;

    const int* esrc = ei;
    const int* edst = ei + N_EDGES;

    char* ws = (char*)d_ws;
    size_t off = 0;
    auto alloc = [&](size_t bytes) { size_t p = off; off = (off + bytes + 255) & ~(size_t)255; return p; };
    float* stats1  = (float*)(ws + alloc(4096 * 4));   // 8 banks x 512 (sum@+col, sumsq@+256+col)
    float* stats2  = (float*)(ws + alloc(4096 * 4));
    int*   segCnt  = (int*)  (ws + alloc(64 * 16 * 4));   // 1 counter per 64B line
    size_t zero_bytes = off;                       // everything above must be zeroed
    unsigned* segBuf = (unsigned*)(ws + alloc((size_t)NSUP * SEGCAP * 4));
    u16*   col_srt = (u16*)  (ws + alloc((size_t)NBKT * CAP * 2));
    u16*   hdr     = (u16*)  (ws + alloc((size_t)NBKT * 32 * 2));
    u16*   xh      = (u16*)  (ws + alloc((size_t)N_NODES * DIM * 2));
    u8*    xf8     = (u8*)   (ws + alloc((size_t)N_NODES * DIM));
    u16*   hb1     = (u16*)  (ws + alloc((size_t)N_NODES * DIM * 2));  // raw h1 bf16
    u8*    h1f8    = (u8*)   (ws + alloc((size_t)N_NODES * DIM));     // raw h1 fp8
    u16*   hb2     = (u16*)  (ws + alloc((size_t)N_NODES * DIM * 2));  // raw h2 bf16
    u16*   Bp1h    = (u16*)  (ws + alloc(256 * 128 * 2));
    u16*   Bp2h    = (u16*)  (ws + alloc(256 * 128 * 2));

    hipMemsetAsync(ws, 0, zero_bytes, stream);

    const int AGB = N_NODES / 16;                    // 3125 exact
    const int EWB4 = (int)(((long)N_NODES * DIM) / 1024);  // 6250 exact
    const int EWB8 = (int)(((long)N_NODES * DIM) / 2048);  // 3125 exact
    const int EDGB = (N_EDGES + 1023) / 1024;        // 782 (4 edges/thread)
    const int PREPB = 32 + EWB4 + EDGB;              // pack + split + binned append

    // prep: pack both B + split x (bf16 + fp8) + LDS-binned segmented bucketing
    k_prep<<<PREPB, 256, 0, stream>>>(W1l, W1r, Bp1h, W2l, W2r, Bp2h, x, xh, xf8,
                                      esrc, edst, segCnt, segBuf, EWB4);

    // per-superkey counting sort -> col_srt (group-CAP layout) + hdr
    k_sort<<<NSUP, 512, 0, stream>>>(segCnt, segBuf, col_srt, hdr);

    // stage 1: fused agg+gemm on x (fp8 gather, bf16 root); writes h1 bf16 + fp8
    k_ag<0, 1><<<AGB, 256, 0, stream>>>(xf8, xh, hdr, col_srt, Bp1h, b1,
                                        stats1, g1, bt1, hb1, h1f8, stats1);

    // stage 2: fused agg+gemm on h1 with BN+relu at operand load (coeffs from stats1)
    k_ag<1, 0><<<AGB, 256, 0, stream>>>(h1f8, hb1, hdr, col_srt, Bp2h, b2,
                                        stats1, g1, bt1, hb2, h1f8, stats2);

    // epilogue: out = relu(bn(h2) + x), coeffs from stats2
    k_bn_add_relu<<<EWB8, 256, 0, stream>>>(hb2, stats2, g2, bt2, x, out);
}